// Round 4
// baseline (128.281 us; speedup 1.0000x reference)
//
#include <hip/hip_runtime.h>
#include <hip/hip_bf16.h>

// Problem constants
#define N_G 32
#define E_N 512
#define IN_D 128
#define OUT_D 64
#define NT 3
#define Q_D 128

// Workspace layout (float elements)
//  (w_src/w_dst/W2T slots retained but unused after qgate->kA merge)
//  s_src  [3][32][512]   @ 24576
//  s_dst  [3][32][512]   @ 73728
//  invsum [32][512]      @ 139264
//  hTg    [32][64][512]  @ 155648  (bf16, TRANSPOSED: [n][d][e], 1048576 ushorts)
//  adj2   [32][512][64]  @ 684032  (ushort 2-bit codes: word u holds j=u+64b at bits 2b)
#define WS_SSRC 24576
#define WS_SDST 73728
#define WS_RINV 139264
#define WS_H    155648
#define WS_ADJ2 684032

typedef const float* fp;
typedef __attribute__((ext_vector_type(8))) short short8x;   // 8 bf16 (A/B frag)
typedef __attribute__((ext_vector_type(4))) float float4x;   // C/D frag

static __device__ inline ushort f2bf(float x) {
  __hip_bfloat16 b = __float2bfloat16(x);
  return *(ushort*)&b;
}
static __device__ inline float bf2f(ushort u) {
  return __uint_as_float((uint)u << 16);
}

// ---------------------------------------------------------------------------
// KA = qgate + k2 merged (dispatch count 4 -> 3; tests the ~10us/dispatch
// gap hypothesis). grid 256: n = b>>3, e-half = b&7 (64 e rows, 2 subtiles).
// Per-block preamble recomputes the tiny qgate MLP for its n (W1/W2 read
// from L2/L3 redundantly, ~384KB/block) -> wv[6][128] + BT (W[2]^T bf16)
// entirely in LDS; then the proven k2 body runs twice (e0, e0+32).
// ---------------------------------------------------------------------------
__global__ __launch_bounds__(256) void kA_qgate_h_s(
    fp X, fp mask, fp qv_g, fp Wt, fp at, fp W1, fp W2,
    float* __restrict__ ws) {
  const int n  = blockIdx.x >> 3;
  const int eh = blockIdx.x & 7;
  __shared__ float qv[128];
  __shared__ float ps[8][132];
  __shared__ float g1s[128], g2s[128];
  __shared__ float gsv[64], gdv[64];
  __shared__ float wv[6 * 128];
  __shared__ ushort BT[64 * 136];   // [d][i] = bf16(W[2][i][d])
  __shared__ ushort A[32 * 136];    // [e][i]
  __shared__ ushort eT[64 * 40];    // [d][e-local]
  const int t = threadIdx.x;
  ushort* hb = (ushort*)(ws + WS_H);

  // ---- BT build: coalesced float4 reads of Wt[2], transposed LDS writes ----
  #pragma unroll
  for (int k = 0; k < 8; k++) {
    int f = k * 1024 + t * 4;            // 0..8191
    int i = f >> 6, d = f & 63;
    float4 v = *(const float4*)&Wt[2 * 8192 + f];
    BT[(d + 0) * 136 + i] = f2bf(v.x);
    BT[(d + 1) * 136 + i] = f2bf(v.y);
    BT[(d + 2) * 136 + i] = f2bf(v.z);
    BT[(d + 3) * 136 + i] = f2bf(v.w);
  }
  if (t < 128) qv[t] = qv_g[n * Q_D + t];
  __syncthreads();

  // ---- qgate preamble: loop over the 3 types (split-K, proven code) ----
  const int h   = t >> 5;               // 0..7 (q-chunk of 16)
  const int cg_ = (t & 31) << 2;        // output col base
  for (int tt = 0; tt < 3; tt++) {
    // layer 1: g1 = relu(qv @ W1[tt])
    {
      float a0 = 0.f, a1 = 0.f, a2 = 0.f, a3 = 0.f;
      const float* Wp = W1 + tt * 16384 + (h * 16) * 128 + cg_;
      #pragma unroll
      for (int q = 0; q < 16; q++) {
        float4 wv4 = *(const float4*)(Wp + q * 128);
        float qq = qv[h * 16 + q];
        a0 += qq * wv4.x; a1 += qq * wv4.y; a2 += qq * wv4.z; a3 += qq * wv4.w;
      }
      ps[h][cg_ + 0] = a0; ps[h][cg_ + 1] = a1;
      ps[h][cg_ + 2] = a2; ps[h][cg_ + 3] = a3;
    }
    __syncthreads();
    if (t < 128) {
      float s = 0.f;
      #pragma unroll
      for (int k = 0; k < 8; k++) s += ps[k][t];
      g1s[t] = s > 0.f ? s : 0.f;
    }
    __syncthreads();
    // layer 2: g2 = sigmoid(g1 @ W2[tt])
    {
      float a0 = 0.f, a1 = 0.f, a2 = 0.f, a3 = 0.f;
      const float* Wp = W2 + tt * 16384 + (h * 16) * 128 + cg_;
      #pragma unroll
      for (int q = 0; q < 16; q++) {
        float4 wv4 = *(const float4*)(Wp + q * 128);
        float qq = g1s[h * 16 + q];
        a0 += qq * wv4.x; a1 += qq * wv4.y; a2 += qq * wv4.z; a3 += qq * wv4.w;
      }
      ps[h][cg_ + 0] = a0; ps[h][cg_ + 1] = a1;
      ps[h][cg_ + 2] = a2; ps[h][cg_ + 3] = a3;
    }
    __syncthreads();
    if (t < 128) {
      float s = 0.f;
      #pragma unroll
      for (int k = 0; k < 8; k++) s += ps[k][t];
      g2s[t] = 1.f / (1.f + __expf(-s));
    }
    __syncthreads();
    if (t < 64) {
      gsv[t] = g2s[t] * at[tt * 128 + t];
      gdv[t] = g2s[64 + t] * at[tt * 128 + 64 + t];
    }
    __syncthreads();
    // w phase: wv[tt][i] = sum_d Wt[tt][i][d]*gs[d]; wv[3+tt] likewise
    {
      const int i = t & 127, hf = t >> 7;
      float as = 0.f, ad = 0.f;
      const float* Wp = Wt + tt * 8192 + i * 64 + hf * 32;
      #pragma unroll
      for (int dj = 0; dj < 8; dj++) {
        float4 wv4 = *(const float4*)(Wp + dj * 4);
        const float* gp = gsv + hf * 32 + dj * 4;
        const float* gq = gdv + hf * 32 + dj * 4;
        as += wv4.x * gp[0] + wv4.y * gp[1] + wv4.z * gp[2] + wv4.w * gp[3];
        ad += wv4.x * gq[0] + wv4.y * gq[1] + wv4.z * gq[2] + wv4.w * gq[3];
      }
      ps[hf][i]     = as;
      ps[2 + hf][i] = ad;
    }
    __syncthreads();
    if (t < 128) {
      wv[tt * 128 + t]       = ps[0][t] + ps[1][t];
      wv[(3 + tt) * 128 + t] = ps[2][t] + ps[3][t];
    }
    __syncthreads();
  }

  // ---- k2 body x2 subtiles (proven round-1 code) ----
  const int w = t >> 6, lane = t & 63;
  const int m15 = lane & 15, quad = lane >> 4;
  const int msub = w & 1, dhalf = w >> 1;

  for (int sub = 0; sub < 2; sub++) {
    const int e0 = eh * 64 + sub * 32;

    #pragma unroll
    for (int k = 0; k < 4; k++) {
      int f = t + 256 * k;                 // 0..1023
      int e = f >> 5, iq = f & 31;
      float4 v = *(const float4*)&X[(n * E_N + e0 + e) * IN_D + iq * 4];
      uint2 pk;
      pk.x = (uint)f2bf(v.x) | ((uint)f2bf(v.y) << 16);
      pk.y = (uint)f2bf(v.z) | ((uint)f2bf(v.w) << 16);
      *(uint2*)&A[e * 136 + iq * 4] = pk;
    }
    __syncthreads();

    float4x acc2[2];
    acc2[0] = (float4x)(0.f); acc2[1] = (float4x)(0.f);
    #pragma unroll
    for (int ks = 0; ks < 4; ks++) {
      short8x af = *(const short8x*)&A[(msub * 16 + m15) * 136 + ks * 32 + quad * 8];
      #pragma unroll
      for (int dd = 0; dd < 2; dd++) {
        short8x bfv = *(const short8x*)&BT[((dhalf * 2 + dd) * 16 + m15) * 136 + ks * 32 + quad * 8];
        acc2[dd] = __builtin_amdgcn_mfma_f32_16x16x32_bf16(af, bfv, acc2[dd], 0, 0, 0);
      }
    }

    if (t < 192) {
      const int e = t / 6, q = t % 6;
      float acc = 0.f;
      #pragma unroll
      for (int i8 = 0; i8 < 16; i8++) {
        uint4 pk = *(const uint4*)&A[e * 136 + i8 * 8];
        const float* wp = &wv[q * 128 + i8 * 8];
        acc += bf2f((ushort)(pk.x & 0xffff)) * wp[0];
        acc += bf2f((ushort)(pk.x >> 16))    * wp[1];
        acc += bf2f((ushort)(pk.y & 0xffff)) * wp[2];
        acc += bf2f((ushort)(pk.y >> 16))    * wp[3];
        acc += bf2f((ushort)(pk.z & 0xffff)) * wp[4];
        acc += bf2f((ushort)(pk.z >> 16))    * wp[5];
        acc += bf2f((ushort)(pk.w & 0xffff)) * wp[6];
        acc += bf2f((ushort)(pk.w >> 16))    * wp[7];
      }
      if (q < 3) ws[WS_SSRC + q * 16384 + n * 512 + e0 + e] = acc;
      else       ws[WS_SDST + (q - 3) * 16384 + n * 512 + e0 + e] = acc;
    }

    // epilogue: C (e=quad*4+rg row, d col) * mask -> eT[d][e] bf16
    float mv[4];
    #pragma unroll
    for (int rg = 0; rg < 4; rg++)
      mv[rg] = mask[n * E_N + e0 + msub * 16 + quad * 4 + rg];
    #pragma unroll
    for (int dd = 0; dd < 2; dd++) {
      int dRow = (dhalf * 2 + dd) * 16 + m15;
      #pragma unroll
      for (int rg = 0; rg < 4; rg++) {
        int e = msub * 16 + quad * 4 + rg;
        eT[dRow * 40 + e] = f2bf(acc2[dd][rg] * mv[rg]);
      }
    }
    __syncthreads();

    // hTg[n][d][e0+e]: one uint4 (8 e) per thread, sector-coalesced
    {
      int d = t >> 2, e8 = t & 3;
      *(uint4*)&hb[(n * 64 + d) * 512 + e0 + e8 * 8] =
          *(const uint4*)&eT[d * 40 + e8 * 8];
    }
  }
}

// ---------------------------------------------------------------------------
// KB: per-row softmax denom + 2-bit adj pack (4096 blocks, wave-per-row).
// Verbatim round-1 k3 (best-measured structure).
// ---------------------------------------------------------------------------
__global__ __launch_bounds__(256) void kB_rowstats(const int* __restrict__ adj,
                                                   float* __restrict__ ws) {
  const int n  = blockIdx.x >> 7;
  const int ib = blockIdx.x & 127;
  __shared__ float sd[3 * 512];
  const int t = threadIdx.x;
  ushort* adj2 = (ushort*)(ws + WS_ADJ2);

  #pragma unroll
  for (int k = 0; k < 6; k++) {
    int idx = t + 256 * k;
    sd[idx] = ws[WS_SDST + (idx >> 9) * 16384 + n * 512 + (idx & 511)];
  }
  __syncthreads();

  const int wave = t >> 6, lane = t & 63;
  const int i = ib * 4 + wave;
  const float s0 = ws[WS_SSRC + 0 * 16384 + n * 512 + i];
  const float s1 = ws[WS_SSRC + 1 * 16384 + n * 512 + i];
  const float s2 = ws[WS_SSRC + 2 * 16384 + n * 512 + i];
  const int* arow = &adj[(n * E_N + i) * E_N];

  float sum = 0.f;
  uint pack = 0;
  #pragma unroll
  for (int b = 0; b < 8; b++) {
    int j = b * 64 + lane;
    int a = arow[j];
    pack |= (uint)(a & 3) << (2 * b);
    if (a > 0) {
      float s = (a == 1) ? s0 : (a == 2 ? s1 : s2);
      float v = s + sd[(a - 1) * 512 + j];
      v = v > 0.f ? v : 0.2f * v;
      sum += __expf(v);
    }
  }
  #pragma unroll
  for (int off = 32; off >= 1; off >>= 1) sum += __shfl_xor(sum, off, 64);
  if (lane == 0) ws[WS_RINV + n * 512 + i] = 1.f / sum;
  adj2[(n * E_N + i) * 64 + lane] = (ushort)pack;   // 128 B/wave coalesced
}

// ---------------------------------------------------------------------------
// KC: out[n,j,d] = sum_i coef[n,i,j]*h[n,i,d] via MFMA, single pass over i.
// Verbatim round-1 k4 (best-measured structure).
// ---------------------------------------------------------------------------
__global__ __launch_bounds__(256) void kC_out(float* __restrict__ ws,
                                              float* __restrict__ out) {
  const int n  = blockIdx.x >> 4;
  const int j0 = (blockIdx.x & 15) << 5;
  __shared__ ushort cT[32 * 136];
  __shared__ ushort hT[64 * 136];   // [d][i-local]
  __shared__ ushort aS[128 * 64];   // adj2 tile [i-local][u]
  __shared__ float sdT[3 * 32];
  __shared__ float ssT[3 * 128];
  __shared__ float riT[128];
  const int t = threadIdx.x;
  const ushort* hb = (const ushort*)(ws + WS_H);
  const ushort* adj2 = (const ushort*)(ws + WS_ADJ2);

  if (t < 96) sdT[t] = ws[WS_SDST + (t >> 5) * 16384 + n * 512 + j0 + (t & 31)];

  const int w = t >> 6, lane = t & 63;
  const int m15 = lane & 15, quad = lane >> 4;
  const int msub = w & 1, dhalf = w >> 1;
  const int c   = t & 31;            // j-local col (coef phase)
  const int rpb = t >> 5;            // 0..7 row-pair base
  const int u     = (j0 & 63) + c;   // ushort index within adj2 row
  const int shift = 2 * (j0 >> 6);   // bit position (block-uniform)

  float4x acc[2];
  acc[0] = (float4x)(0.f); acc[1] = (float4x)(0.f);

  for (int it = 0; it < 4; it++) {
    const int i0 = it << 7;

    #pragma unroll
    for (int k = 0; k < 4; k++) {
      int f = t + 256 * k;               // 0..1023
      int d = f >> 4, i16 = f & 15;
      *(uint4*)&hT[d * 136 + i16 * 8] =
          *(const uint4*)&hb[(n * 64 + d) * 512 + i0 + i16 * 8];
    }
    #pragma unroll
    for (int k = 0; k < 4; k++) {
      int f = t + 256 * k;               // 0..1023
      int r = f >> 3, c8 = f & 7;
      *(uint4*)&aS[r * 64 + c8 * 8] =
          *(const uint4*)&adj2[(size_t)(n * E_N + i0 + r) * 64 + c8 * 8];
    }
    #pragma unroll
    for (int k = 0; k < 2; k++) {
      int idx = t + 256 * k;
      if (idx < 128) riT[idx] = ws[WS_RINV + n * 512 + i0 + idx];
      else {
        int j2 = idx - 128;
        ssT[j2] = ws[WS_SSRC + (j2 >> 7) * 16384 + n * 512 + i0 + (j2 & 127)];
      }
    }
    __syncthreads();

    // coef -> bf16 pairs -> cT[j][i]; adj codes from LDS aS
    #pragma unroll
    for (int k = 0; k < 8; k++) {
      int r0 = 2 * (rpb + 8 * k);
      uint pack = 0;
      int a = (aS[r0 * 64 + u] >> shift) & 3;
      if (a > 0) {
        float v = ssT[(a - 1) * 128 + r0] + sdT[(a - 1) * 32 + c];
        v = v > 0.f ? v : 0.2f * v;
        pack = f2bf(__expf(v) * riT[r0]);
      }
      a = (aS[(r0 + 1) * 64 + u] >> shift) & 3;
      if (a > 0) {
        float v = ssT[(a - 1) * 128 + r0 + 1] + sdT[(a - 1) * 32 + c];
        v = v > 0.f ? v : 0.2f * v;
        pack |= (uint)f2bf(__expf(v) * riT[r0 + 1]) << 16;
      }
      *(uint*)&cT[c * 136 + r0] = pack;
    }
    __syncthreads();

    #pragma unroll
    for (int ks = 0; ks < 4; ks++) {
      short8x af = *(const short8x*)&cT[(msub * 16 + m15) * 136 + ks * 32 + quad * 8];
      #pragma unroll
      for (int dd = 0; dd < 2; dd++) {
        short8x bfv = *(const short8x*)&hT[((dhalf * 2 + dd) * 16 + m15) * 136 + ks * 32 + quad * 8];
        acc[dd] = __builtin_amdgcn_mfma_f32_16x16x32_bf16(af, bfv, acc[dd], 0, 0, 0);
      }
    }
    __syncthreads();
  }

  #pragma unroll
  for (int dd = 0; dd < 2; dd++)
    #pragma unroll
    for (int rg = 0; rg < 4; rg++) {
      int j = j0 + msub * 16 + quad * 4 + rg;
      out[(n * E_N + j) * 64 + (dhalf * 2 + dd) * 16 + m15] = acc[dd][rg];
    }
}

extern "C" void kernel_launch(void* const* d_in, const int* in_sizes, int n_in,
                              void* d_out, int out_size, void* d_ws, size_t ws_size,
                              hipStream_t stream) {
  fp input_state  = (fp)d_in[0];
  const int* adj  = (const int*)d_in[1];
  fp query_vec    = (fp)d_in[2];
  fp node_mask    = (fp)d_in[3];
  fp W_type       = (fp)d_in[4];
  fp a_type       = (fp)d_in[5];
  fp qattn_W1     = (fp)d_in[6];
  fp qattn_W2     = (fp)d_in[7];
  float* out = (float*)d_out;
  float* ws  = (float*)d_ws;

  kA_qgate_h_s<<<256, 256, 0, stream>>>(input_state, node_mask, query_vec,
                                        W_type, a_type, qattn_W1, qattn_W2, ws);
  kB_rowstats<<<32 * 128, 256, 0, stream>>>(adj, ws);
  kC_out<<<32 * 16, 256, 0, stream>>>(ws, out);
}

// Round 6
// 127.249 us; speedup vs baseline: 1.0081x; 1.0081x over previous
//
#include <hip/hip_runtime.h>
#include <hip/hip_bf16.h>

// Problem constants
#define N_G 32
#define E_N 512
#define IN_D 128
#define OUT_D 64
#define NT 3
#define Q_D 128

// Workspace layout (float elements)
//  w_src  [3][32][128]   @ 0
//  w_dst  [3][32][128]   @ 12288
//  s_src  [3][32][512]   @ 24576
//  s_dst  [3][32][512]   @ 73728
//  invsum [32][512]      @ 139264
//  hTg    [32][64][512]  @ 155648  (bf16, TRANSPOSED: [n][d][e], 1048576 ushorts)
//  W2T    [64][128]      @ 679936  (bf16, 8192 ushorts) W[2]^T
//  adj2   [32][512][64]  @ 684032  (ushort 2-bit codes: word u holds j=u+64b at bits 2b)
#define WS_WSRC 0
#define WS_WDST 12288
#define WS_SSRC 24576
#define WS_SDST 73728
#define WS_RINV 139264
#define WS_H    155648
#define WS_W2T  679936
#define WS_ADJ2 684032

typedef const float* fp;
typedef __attribute__((ext_vector_type(8))) short short8x;   // 8 bf16 (A/B frag)
typedef __attribute__((ext_vector_type(4))) float float4x;   // C/D frag

static __device__ inline ushort f2bf(float x) {
  __hip_bfloat16 b = __float2bfloat16(x);
  return *(ushort*)&b;
}
static __device__ inline float bf2f(ushort u) {
  return __uint_as_float((uint)u << 16);
}

// ---------------------------------------------------------------------------
// K1: blocks 0..95: qgate MLP (round-1 verbatim, 512 threads, split-K).
//     blocks 96..2143: pack raw adj (33.5 MB) into 2-bit adj2 (2 MB),
//     8 rows/block (one per wave). The adj stream is independent of the
//     qgate chain; overlapping them hides the compulsory HBM read.
// ---------------------------------------------------------------------------
__global__ __launch_bounds__(512) void k1_qgate_pack(
    fp qv_g, fp Wt, fp at, fp W1, fp W2,
    const int* __restrict__ adj, float* __restrict__ ws) {
  const int b = blockIdx.x;
  const int t = threadIdx.x;

  if (b >= 96) {
    // ---- adj pack: 2048 blocks x 8 waves, one row per wave ----
    const int w = t >> 6, lane = t & 63;
    const int R = (b - 96) * 8 + w;          // 0..16383 (= n*512 + i)
    const int* arow = adj + (size_t)R * E_N;
    uint pack = 0;
    #pragma unroll
    for (int bb = 0; bb < 8; bb++) {
      int a = arow[bb * 64 + lane];
      pack |= (uint)(a & 3) << (2 * bb);
    }
    ((ushort*)(ws + WS_ADJ2))[(size_t)R * 64 + lane] = (ushort)pack;
    return;
  }

  // ---- qgate: round-1 verbatim (512 threads, 16-deep split-K) ----
  const int tb = b >> 5;
  const int n  = b & 31;
  __shared__ float qv[128];
  __shared__ float ps[16][132];
  __shared__ float g1s[128], g2s[128];
  __shared__ float gsv[64], gdv[64];
  const int h  = t >> 5;          // 0..15 (q-chunk)
  const int cg = (t & 31) << 2;   // output column base

  if (t < 128) qv[t] = qv_g[n * Q_D + t];
  __syncthreads();

  // layer 1: g1 = relu(qv @ W1[tb])
  {
    float a0 = 0.f, a1 = 0.f, a2 = 0.f, a3 = 0.f;
    const float* Wp = W1 + tb * 16384 + (h * 8) * 128 + cg;
    #pragma unroll
    for (int q = 0; q < 8; q++) {
      float4 wv = *(const float4*)(Wp + q * 128);
      float qq = qv[h * 8 + q];
      a0 += qq * wv.x; a1 += qq * wv.y; a2 += qq * wv.z; a3 += qq * wv.w;
    }
    ps[h][cg + 0] = a0; ps[h][cg + 1] = a1;
    ps[h][cg + 2] = a2; ps[h][cg + 3] = a3;
  }
  __syncthreads();
  if (t < 128) {
    float s = 0.f;
    #pragma unroll
    for (int k = 0; k < 16; k++) s += ps[k][t];
    g1s[t] = s > 0.f ? s : 0.f;
  }
  __syncthreads();

  // layer 2: g2 = sigmoid(g1 @ W2[tb])
  {
    float a0 = 0.f, a1 = 0.f, a2 = 0.f, a3 = 0.f;
    const float* Wp = W2 + tb * 16384 + (h * 8) * 128 + cg;
    #pragma unroll
    for (int q = 0; q < 8; q++) {
      float4 wv = *(const float4*)(Wp + q * 128);
      float qq = g1s[h * 8 + q];
      a0 += qq * wv.x; a1 += qq * wv.y; a2 += qq * wv.z; a3 += qq * wv.w;
    }
    ps[h][cg + 0] = a0; ps[h][cg + 1] = a1;
    ps[h][cg + 2] = a2; ps[h][cg + 3] = a3;
  }
  __syncthreads();
  if (t < 128) {
    float s = 0.f;
    #pragma unroll
    for (int k = 0; k < 16; k++) s += ps[k][t];
    g2s[t] = 1.f / (1.f + __expf(-s));
  }
  __syncthreads();
  if (t < 64) {
    gsv[t] = g2s[t] * at[tb * 128 + t];
    gdv[t] = g2s[64 + t] * at[tb * 128 + 64 + t];
  }
  __syncthreads();

  // w phase: as[i] = sum_d Wt[tb][i][d]*gs[d]; ad likewise.
  if (t < 256) {
    const int i = t & 127, hf = t >> 7;
    float as = 0.f, ad = 0.f;
    const float* Wp = Wt + tb * 8192 + i * 64 + hf * 32;
    #pragma unroll
    for (int dj = 0; dj < 8; dj++) {
      float4 wv = *(const float4*)(Wp + dj * 4);
      const float* gp = gsv + hf * 32 + dj * 4;
      const float* gq = gdv + hf * 32 + dj * 4;
      as += wv.x * gp[0] + wv.y * gp[1] + wv.z * gp[2] + wv.w * gp[3];
      ad += wv.x * gq[0] + wv.y * gq[1] + wv.z * gq[2] + wv.w * gq[3];
    }
    ps[hf][i]     = as;
    ps[2 + hf][i] = ad;
  }
  __syncthreads();
  if (t < 128) {
    ws[WS_WSRC + tb * 4096 + n * 128 + t] = ps[0][t] + ps[1][t];
    ws[WS_WDST + tb * 4096 + n * 128 + t] = ps[2][t] + ps[3][t];
  }

  // W2T: 8192 ushorts total; 32 tb==2 blocks x 128 threads x 2 elems
  if (tb == 2 && t < 128) {
    int f = n * 256 + t * 2;            // even flat index into [d][i]
    int d = f >> 7, i0 = f & 127;
    uint lo = f2bf(Wt[2 * 8192 + i0 * 64 + d]);
    uint hi = f2bf(Wt[2 * 8192 + (i0 + 1) * 64 + d]);
    ((uint*)(ws + WS_W2T))[f >> 1] = lo | (hi << 16);
  }
}

// ---------------------------------------------------------------------------
// K2: h = mask * X@W[2] via MFMA, stored TRANSPOSED hTg[n][d][e] (bf16);
//     s_{src,dst}[t,n,e] = X . w_{src,dst}
// grid 512 (n = b>>4, e-tile 32 = b&15), block 256 = 4 waves. (round-1)
// ---------------------------------------------------------------------------
__global__ __launch_bounds__(256) void k2_h_s(fp X, fp mask,
                                              float* __restrict__ ws) {
  const int n  = blockIdx.x >> 4;
  const int e0 = (blockIdx.x & 15) << 5;
  __shared__ ushort A[32 * 136];    // [e][i], stride 136 (272B = 16*17)
  __shared__ ushort BT[64 * 136];   // [d][i]
  __shared__ ushort eT[64 * 40];    // [d][e-local], stride 40 (80B, 16B-mult)
  __shared__ float wv[6 * 128];
  const int t = threadIdx.x;
  ushort* hb = (ushort*)(ws + WS_H);
  const ushort* w2t = (const ushort*)(ws + WS_W2T);

  #pragma unroll
  for (int k = 0; k < 4; k++) {
    int f = t + 256 * k;                 // 0..1023
    int e = f >> 5, iq = f & 31;
    float4 v = *(const float4*)&X[(n * E_N + e0 + e) * IN_D + iq * 4];
    uint2 pk;
    pk.x = (uint)f2bf(v.x) | ((uint)f2bf(v.y) << 16);
    pk.y = (uint)f2bf(v.z) | ((uint)f2bf(v.w) << 16);
    *(uint2*)&A[e * 136 + iq * 4] = pk;
  }
  #pragma unroll
  for (int k = 0; k < 4; k++) {
    int f = t + 256 * k;                 // 0..1023
    int d = f >> 4, iq8 = f & 15;
    *(uint4*)&BT[d * 136 + iq8 * 8] = *(const uint4*)&w2t[d * 128 + iq8 * 8];
  }
  #pragma unroll
  for (int k = 0; k < 3; k++) {
    int idx = t + 256 * k;               // 768
    int row = idx >> 7, i = idx & 127;
    wv[idx] = (row < 3) ? ws[WS_WSRC + row * 4096 + n * 128 + i]
                        : ws[WS_WDST + (row - 3) * 4096 + n * 128 + i];
  }
  __syncthreads();

  const int w = t >> 6, lane = t & 63;
  const int m15 = lane & 15, quad = lane >> 4;
  const int msub = w & 1, dhalf = w >> 1;

  float4x acc2[2];
  acc2[0] = (float4x)(0.f); acc2[1] = (float4x)(0.f);
  #pragma unroll
  for (int ks = 0; ks < 4; ks++) {
    short8x af = *(const short8x*)&A[(msub * 16 + m15) * 136 + ks * 32 + quad * 8];
    #pragma unroll
    for (int dd = 0; dd < 2; dd++) {
      short8x bfv = *(const short8x*)&BT[((dhalf * 2 + dd) * 16 + m15) * 136 + ks * 32 + quad * 8];
      acc2[dd] = __builtin_amdgcn_mfma_f32_16x16x32_bf16(af, bfv, acc2[dd], 0, 0, 0);
    }
  }

  if (t < 192) {
    const int e = t / 6, q = t % 6;
    float acc = 0.f;
    #pragma unroll
    for (int i8 = 0; i8 < 16; i8++) {
      uint4 pk = *(const uint4*)&A[e * 136 + i8 * 8];
      const float* wp = &wv[q * 128 + i8 * 8];
      acc += bf2f((ushort)(pk.x & 0xffff)) * wp[0];
      acc += bf2f((ushort)(pk.x >> 16))    * wp[1];
      acc += bf2f((ushort)(pk.y & 0xffff)) * wp[2];
      acc += bf2f((ushort)(pk.y >> 16))    * wp[3];
      acc += bf2f((ushort)(pk.z & 0xffff)) * wp[4];
      acc += bf2f((ushort)(pk.z >> 16))    * wp[5];
      acc += bf2f((ushort)(pk.w & 0xffff)) * wp[6];
      acc += bf2f((ushort)(pk.w >> 16))    * wp[7];
    }
    if (q < 3) ws[WS_SSRC + q * 16384 + n * 512 + e0 + e] = acc;
    else       ws[WS_SDST + (q - 3) * 16384 + n * 512 + e0 + e] = acc;
  }

  // epilogue: C (e=quad*4+rg row, d col) * mask -> eT[d][e] bf16
  float mv[4];
  #pragma unroll
  for (int rg = 0; rg < 4; rg++)
    mv[rg] = mask[n * E_N + e0 + msub * 16 + quad * 4 + rg];
  #pragma unroll
  for (int dd = 0; dd < 2; dd++) {
    int dRow = (dhalf * 2 + dd) * 16 + m15;
    #pragma unroll
    for (int rg = 0; rg < 4; rg++) {
      int e = msub * 16 + quad * 4 + rg;
      eT[dRow * 40 + e] = f2bf(acc2[dd][rg] * mv[rg]);
    }
  }
  __syncthreads();

  // hTg[n][d][e0+e]: one uint4 (8 e) per thread, sector-coalesced
  {
    int d = t >> 2, e8 = t & 3;
    *(uint4*)&hb[(n * 64 + d) * 512 + e0 + e8 * 8] =
        *(const uint4*)&eT[d * 40 + e8 * 8];
  }
}

// ---------------------------------------------------------------------------
// K3: per-row softmax denom from PACKED adj2 (2 MB instead of 33.5 MB raw).
// grid 512 (n = b>>4, natural order — NO swizzle), block 256, 8 rows/wave.
// ---------------------------------------------------------------------------
__global__ __launch_bounds__(256) void k3_rows(float* __restrict__ ws) {
  const int n  = blockIdx.x >> 4;
  const int rb = (blockIdx.x & 15) << 5;   // 32-row tile base
  __shared__ float sd[3 * 512];
  const int t = threadIdx.x;
  const ushort* adj2 = (const ushort*)(ws + WS_ADJ2);

  #pragma unroll
  for (int k = 0; k < 6; k++) {
    int idx = t + 256 * k;
    sd[idx] = ws[WS_SDST + (idx >> 9) * 16384 + n * 512 + (idx & 511)];
  }
  __syncthreads();

  const int wave = t >> 6, lane = t & 63;
  #pragma unroll
  for (int rr = 0; rr < 8; rr++) {
    const int i = rb + wave * 8 + rr;
    const float s0 = ws[WS_SSRC + 0 * 16384 + n * 512 + i];
    const float s1 = ws[WS_SSRC + 1 * 16384 + n * 512 + i];
    const float s2 = ws[WS_SSRC + 2 * 16384 + n * 512 + i];
    uint pk = adj2[(size_t)(n * E_N + i) * 64 + lane];

    float sum = 0.f;
    #pragma unroll
    for (int bb = 0; bb < 8; bb++) {
      int a = (pk >> (2 * bb)) & 3;
      if (a > 0) {
        float s = (a == 1) ? s0 : (a == 2 ? s1 : s2);
        float v = s + sd[(a - 1) * 512 + bb * 64 + lane];
        v = v > 0.f ? v : 0.2f * v;
        sum += __expf(v);
      }
    }
    #pragma unroll
    for (int off = 32; off >= 1; off >>= 1) sum += __shfl_xor(sum, off, 64);
    if (lane == 0) ws[WS_RINV + n * 512 + i] = 1.f / sum;
  }
}

// ---------------------------------------------------------------------------
// K4: out[n,j,d] = sum_i coef[n,i,j]*h[n,i,d] via MFMA, single pass over i.
// grid 32*16 (n = b>>4), block 256 = 4 waves. (round-1 verbatim)
// ---------------------------------------------------------------------------
__global__ __launch_bounds__(256) void k4_out(float* __restrict__ ws,
                                              float* __restrict__ out) {
  const int n  = blockIdx.x >> 4;
  const int j0 = (blockIdx.x & 15) << 5;
  __shared__ ushort cT[32 * 136];
  __shared__ ushort hT[64 * 136];   // [d][i-local]
  __shared__ ushort aS[128 * 64];   // adj2 tile [i-local][u]
  __shared__ float sdT[3 * 32];
  __shared__ float ssT[3 * 128];
  __shared__ float riT[128];
  const int t = threadIdx.x;
  const ushort* hb = (const ushort*)(ws + WS_H);
  const ushort* adj2 = (const ushort*)(ws + WS_ADJ2);

  if (t < 96) sdT[t] = ws[WS_SDST + (t >> 5) * 16384 + n * 512 + j0 + (t & 31)];

  const int w = t >> 6, lane = t & 63;
  const int m15 = lane & 15, quad = lane >> 4;
  const int msub = w & 1, dhalf = w >> 1;
  const int c   = t & 31;            // j-local col (coef phase)
  const int rpb = t >> 5;            // 0..7 row-pair base
  const int u     = (j0 & 63) + c;   // ushort index within adj2 row
  const int shift = 2 * (j0 >> 6);   // bit position (block-uniform)

  float4x acc[2];
  acc[0] = (float4x)(0.f); acc[1] = (float4x)(0.f);

  for (int it = 0; it < 4; it++) {
    const int i0 = it << 7;

    // hT: 8192 ushorts = 1024 uint4, coalesced both sides
    #pragma unroll
    for (int k = 0; k < 4; k++) {
      int f = t + 256 * k;               // 0..1023
      int d = f >> 4, i16 = f & 15;
      *(uint4*)&hT[d * 136 + i16 * 8] =
          *(const uint4*)&hb[(n * 64 + d) * 512 + i0 + i16 * 8];
    }
    // adj2 tile: 8192 ushorts = 1024 uint4, coalesced
    #pragma unroll
    for (int k = 0; k < 4; k++) {
      int f = t + 256 * k;               // 0..1023
      int r = f >> 3, c8 = f & 7;
      *(uint4*)&aS[r * 64 + c8 * 8] =
          *(const uint4*)&adj2[(size_t)(n * E_N + i0 + r) * 64 + c8 * 8];
    }
    // riT/ssT: 512 floats
    #pragma unroll
    for (int k = 0; k < 2; k++) {
      int idx = t + 256 * k;
      if (idx < 128) riT[idx] = ws[WS_RINV + n * 512 + i0 + idx];
      else {
        int j2 = idx - 128;
        ssT[j2] = ws[WS_SSRC + (j2 >> 7) * 16384 + n * 512 + i0 + (j2 & 127)];
      }
    }
    __syncthreads();

    // coef -> bf16 pairs -> cT[j][i]; adj codes from LDS aS
    #pragma unroll
    for (int k = 0; k < 8; k++) {
      int r0 = 2 * (rpb + 8 * k);
      uint pack = 0;
      int a = (aS[r0 * 64 + u] >> shift) & 3;
      if (a > 0) {
        float v = ssT[(a - 1) * 128 + r0] + sdT[(a - 1) * 32 + c];
        v = v > 0.f ? v : 0.2f * v;
        pack = f2bf(__expf(v) * riT[r0]);
      }
      a = (aS[(r0 + 1) * 64 + u] >> shift) & 3;
      if (a > 0) {
        float v = ssT[(a - 1) * 128 + r0 + 1] + sdT[(a - 1) * 32 + c];
        v = v > 0.f ? v : 0.2f * v;
        pack |= (uint)f2bf(__expf(v) * riT[r0 + 1]) << 16;
      }
      *(uint*)&cT[c * 136 + r0] = pack;
    }
    __syncthreads();

    #pragma unroll
    for (int ks = 0; ks < 4; ks++) {
      short8x af = *(const short8x*)&cT[(msub * 16 + m15) * 136 + ks * 32 + quad * 8];
      #pragma unroll
      for (int dd = 0; dd < 2; dd++) {
        short8x bfv = *(const short8x*)&hT[((dhalf * 2 + dd) * 16 + m15) * 136 + ks * 32 + quad * 8];
        acc[dd] = __builtin_amdgcn_mfma_f32_16x16x32_bf16(af, bfv, acc[dd], 0, 0, 0);
      }
    }
    __syncthreads();
  }

  #pragma unroll
  for (int dd = 0; dd < 2; dd++)
    #pragma unroll
    for (int rg = 0; rg < 4; rg++) {
      int j = j0 + msub * 16 + quad * 4 + rg;
      out[(n * E_N + j) * 64 + (dhalf * 2 + dd) * 16 + m15] = acc[dd][rg];
    }
}

extern "C" void kernel_launch(void* const* d_in, const int* in_sizes, int n_in,
                              void* d_out, int out_size, void* d_ws, size_t ws_size,
                              hipStream_t stream) {
  fp input_state  = (fp)d_in[0];
  const int* adj  = (const int*)d_in[1];
  fp query_vec    = (fp)d_in[2];
  fp node_mask    = (fp)d_in[3];
  fp W_type       = (fp)d_in[4];
  fp a_type       = (fp)d_in[5];
  fp qattn_W1     = (fp)d_in[6];
  fp qattn_W2     = (fp)d_in[7];
  float* out = (float*)d_out;
  float* ws  = (float*)d_ws;

  k1_qgate_pack<<<96 + 2048, 512, 0, stream>>>(query_vec, W_type, a_type,
                                               qattn_W1, qattn_W2, adj, ws);
  k2_h_s<<<512, 256, 0, stream>>>(input_state, node_mask, ws);
  k3_rows<<<512, 256, 0, stream>>>(ws);
  k4_out<<<32 * 16, 256, 0, stream>>>(ws, out);
}

// Round 7
// 123.469 us; speedup vs baseline: 1.0390x; 1.0306x over previous
//
#include <hip/hip_runtime.h>
#include <hip/hip_bf16.h>

// Problem constants
#define N_G 32
#define E_N 512
#define IN_D 128
#define OUT_D 64
#define NT 3
#define Q_D 128

// Workspace layout (float elements)
//  w_src  [3][32][128]   @ 0
//  w_dst  [3][32][128]   @ 12288
//  s_src  [3][32][512]   @ 24576
//  s_dst  [3][32][512]   @ 73728
//  invsum [32][512]      @ 139264
//  hTg    [32][64][512]  @ 155648  (bf16, TRANSPOSED: [n][d][e], 1048576 ushorts)
//  W2T    [64][128]      @ 679936  (bf16, 8192 ushorts) W[2]^T
//  adj2   [32][512][64]  @ 684032  (ushort 2-bit codes: word u holds j=u+64b at bits 2b)
#define WS_WSRC 0
#define WS_WDST 12288
#define WS_SSRC 24576
#define WS_SDST 73728
#define WS_RINV 139264
#define WS_H    155648
#define WS_W2T  679936
#define WS_ADJ2 684032

typedef const float* fp;
typedef __attribute__((ext_vector_type(8))) short short8x;   // 8 bf16 (A/B frag)
typedef __attribute__((ext_vector_type(4))) float float4x;   // C/D frag

static __device__ inline ushort f2bf(float x) {
  __hip_bfloat16 b = __float2bfloat16(x);
  return *(ushort*)&b;
}
static __device__ inline float bf2f(ushort u) {
  return __uint_as_float((uint)u << 16);
}

// ---------------------------------------------------------------------------
// K1: qg = sigmoid(relu(qv@W1)@W2); w_{src,dst}[t,n,i] = sum_d W[t,i,d]*qg*a
// t==2 blocks additionally write W2T (bf16 W[2]^T [d][i]) for k2's B operand.
//
// Latency-optimized: 512 threads/block (8 waves). Each matvec layer is
// split-K: thread (h=t>>5, cg=(t&31)*4) owns 4 outputs x 8-wide q-chunk,
// 8 independent float4 loads all in flight, dependent-FMA chain 8 long.
// LDS partial-sum reduce (stride 132 to break the 128-stride bank alias).
// ---------------------------------------------------------------------------
__global__ __launch_bounds__(512) void k1_qgate(fp qv_g, fp Wt, fp at,
                                                fp W1, fp W2,
                                                float* __restrict__ ws) {
  const int tb = blockIdx.x >> 5;
  const int n  = blockIdx.x & 31;
  __shared__ float qv[128];
  __shared__ float ps[16][132];
  __shared__ float g1s[128], g2s[128];
  __shared__ float gsv[64], gdv[64];
  const int t  = threadIdx.x;
  const int h  = t >> 5;          // 0..15 (q-chunk)
  const int cg = (t & 31) << 2;   // output column base

  if (t < 128) qv[t] = qv_g[n * Q_D + t];
  __syncthreads();

  // layer 1: g1 = relu(qv @ W1[tb])
  {
    float a0 = 0.f, a1 = 0.f, a2 = 0.f, a3 = 0.f;
    const float* Wp = W1 + tb * 16384 + (h * 8) * 128 + cg;
    #pragma unroll
    for (int q = 0; q < 8; q++) {
      float4 wv = *(const float4*)(Wp + q * 128);
      float qq = qv[h * 8 + q];
      a0 += qq * wv.x; a1 += qq * wv.y; a2 += qq * wv.z; a3 += qq * wv.w;
    }
    ps[h][cg + 0] = a0; ps[h][cg + 1] = a1;
    ps[h][cg + 2] = a2; ps[h][cg + 3] = a3;
  }
  __syncthreads();
  if (t < 128) {
    float s = 0.f;
    #pragma unroll
    for (int k = 0; k < 16; k++) s += ps[k][t];
    g1s[t] = s > 0.f ? s : 0.f;
  }
  __syncthreads();

  // layer 2: g2 = sigmoid(g1 @ W2[tb])
  {
    float a0 = 0.f, a1 = 0.f, a2 = 0.f, a3 = 0.f;
    const float* Wp = W2 + tb * 16384 + (h * 8) * 128 + cg;
    #pragma unroll
    for (int q = 0; q < 8; q++) {
      float4 wv = *(const float4*)(Wp + q * 128);
      float qq = g1s[h * 8 + q];
      a0 += qq * wv.x; a1 += qq * wv.y; a2 += qq * wv.z; a3 += qq * wv.w;
    }
    ps[h][cg + 0] = a0; ps[h][cg + 1] = a1;
    ps[h][cg + 2] = a2; ps[h][cg + 3] = a3;
  }
  __syncthreads();
  if (t < 128) {
    float s = 0.f;
    #pragma unroll
    for (int k = 0; k < 16; k++) s += ps[k][t];
    g2s[t] = 1.f / (1.f + __expf(-s));
  }
  __syncthreads();
  if (t < 64) {
    gsv[t] = g2s[t] * at[tb * 128 + t];
    gdv[t] = g2s[64 + t] * at[tb * 128 + 64 + t];
  }
  __syncthreads();

  // w phase: as[i] = sum_d Wt[tb][i][d]*gs[d]; ad likewise. 256 threads,
  // thread (i = t&127, hf = t>>7) covers d in [hf*32, hf*32+32).
  if (t < 256) {
    const int i = t & 127, hf = t >> 7;
    float as = 0.f, ad = 0.f;
    const float* Wp = Wt + tb * 8192 + i * 64 + hf * 32;
    #pragma unroll
    for (int dj = 0; dj < 8; dj++) {
      float4 wv = *(const float4*)(Wp + dj * 4);
      const float* gp = gsv + hf * 32 + dj * 4;
      const float* gq = gdv + hf * 32 + dj * 4;
      as += wv.x * gp[0] + wv.y * gp[1] + wv.z * gp[2] + wv.w * gp[3];
      ad += wv.x * gq[0] + wv.y * gq[1] + wv.z * gq[2] + wv.w * gq[3];
    }
    ps[hf][i]     = as;
    ps[2 + hf][i] = ad;
  }
  __syncthreads();
  if (t < 128) {
    ws[WS_WSRC + tb * 4096 + n * 128 + t] = ps[0][t] + ps[1][t];
    ws[WS_WDST + tb * 4096 + n * 128 + t] = ps[2][t] + ps[3][t];
  }

  // W2T: 8192 ushorts total; 32 t==2 blocks x 128 threads x 2 elems
  if (tb == 2 && t < 128) {
    int f = n * 256 + t * 2;            // even flat index into [d][i]
    int d = f >> 7, i0 = f & 127;
    uint lo = f2bf(Wt[2 * 8192 + i0 * 64 + d]);
    uint hi = f2bf(Wt[2 * 8192 + (i0 + 1) * 64 + d]);
    ((uint*)(ws + WS_W2T))[f >> 1] = lo | (hi << 16);
  }
}

// ---------------------------------------------------------------------------
// K2: h = mask * X@W[2] via MFMA, stored TRANSPOSED hTg[n][d][e] (bf16);
//     s_{src,dst}[t,n,e] = X . w_{src,dst}
// grid 512 (n = b>>4, e-tile 32 = b&15), block 256 = 4 waves.
// ---------------------------------------------------------------------------
__global__ __launch_bounds__(256) void k2_h_s(fp X, fp mask,
                                              float* __restrict__ ws) {
  const int n  = blockIdx.x >> 4;
  const int e0 = (blockIdx.x & 15) << 5;
  __shared__ ushort A[32 * 136];    // [e][i], stride 136 (272B = 16*17)
  __shared__ ushort BT[64 * 136];   // [d][i]
  __shared__ ushort eT[64 * 40];    // [d][e-local], stride 40 (80B, 16B-mult)
  __shared__ float wv[6 * 128];
  const int t = threadIdx.x;
  ushort* hb = (ushort*)(ws + WS_H);
  const ushort* w2t = (const ushort*)(ws + WS_W2T);

  #pragma unroll
  for (int k = 0; k < 4; k++) {
    int f = t + 256 * k;                 // 0..1023
    int e = f >> 5, iq = f & 31;
    float4 v = *(const float4*)&X[(n * E_N + e0 + e) * IN_D + iq * 4];
    uint2 pk;
    pk.x = (uint)f2bf(v.x) | ((uint)f2bf(v.y) << 16);
    pk.y = (uint)f2bf(v.z) | ((uint)f2bf(v.w) << 16);
    *(uint2*)&A[e * 136 + iq * 4] = pk;
  }
  #pragma unroll
  for (int k = 0; k < 4; k++) {
    int f = t + 256 * k;                 // 0..1023
    int d = f >> 4, iq8 = f & 15;
    *(uint4*)&BT[d * 136 + iq8 * 8] = *(const uint4*)&w2t[d * 128 + iq8 * 8];
  }
  #pragma unroll
  for (int k = 0; k < 3; k++) {
    int idx = t + 256 * k;               // 768
    int row = idx >> 7, i = idx & 127;
    wv[idx] = (row < 3) ? ws[WS_WSRC + row * 4096 + n * 128 + i]
                        : ws[WS_WDST + (row - 3) * 4096 + n * 128 + i];
  }
  __syncthreads();

  const int w = t >> 6, lane = t & 63;
  const int m15 = lane & 15, quad = lane >> 4;
  const int msub = w & 1, dhalf = w >> 1;

  float4x acc2[2];
  acc2[0] = (float4x)(0.f); acc2[1] = (float4x)(0.f);
  #pragma unroll
  for (int ks = 0; ks < 4; ks++) {
    short8x af = *(const short8x*)&A[(msub * 16 + m15) * 136 + ks * 32 + quad * 8];
    #pragma unroll
    for (int dd = 0; dd < 2; dd++) {
      short8x bfv = *(const short8x*)&BT[((dhalf * 2 + dd) * 16 + m15) * 136 + ks * 32 + quad * 8];
      acc2[dd] = __builtin_amdgcn_mfma_f32_16x16x32_bf16(af, bfv, acc2[dd], 0, 0, 0);
    }
  }

  if (t < 192) {
    const int e = t / 6, q = t % 6;
    float acc = 0.f;
    #pragma unroll
    for (int i8 = 0; i8 < 16; i8++) {
      uint4 pk = *(const uint4*)&A[e * 136 + i8 * 8];
      const float* wp = &wv[q * 128 + i8 * 8];
      acc += bf2f((ushort)(pk.x & 0xffff)) * wp[0];
      acc += bf2f((ushort)(pk.x >> 16))    * wp[1];
      acc += bf2f((ushort)(pk.y & 0xffff)) * wp[2];
      acc += bf2f((ushort)(pk.y >> 16))    * wp[3];
      acc += bf2f((ushort)(pk.z & 0xffff)) * wp[4];
      acc += bf2f((ushort)(pk.z >> 16))    * wp[5];
      acc += bf2f((ushort)(pk.w & 0xffff)) * wp[6];
      acc += bf2f((ushort)(pk.w >> 16))    * wp[7];
    }
    if (q < 3) ws[WS_SSRC + q * 16384 + n * 512 + e0 + e] = acc;
    else       ws[WS_SDST + (q - 3) * 16384 + n * 512 + e0 + e] = acc;
  }

  // epilogue: C (e=quad*4+rg row, d col) * mask -> eT[d][e] bf16
  float mv[4];
  #pragma unroll
  for (int rg = 0; rg < 4; rg++)
    mv[rg] = mask[n * E_N + e0 + msub * 16 + quad * 4 + rg];
  #pragma unroll
  for (int dd = 0; dd < 2; dd++) {
    int dRow = (dhalf * 2 + dd) * 16 + m15;
    #pragma unroll
    for (int rg = 0; rg < 4; rg++) {
      int e = msub * 16 + quad * 4 + rg;
      eT[dRow * 40 + e] = f2bf(acc2[dd][rg] * mv[rg]);
    }
  }
  __syncthreads();

  // hTg[n][d][e0+e]: one uint4 (8 e) per thread, sector-coalesced
  {
    int d = t >> 2, e8 = t & 3;
    *(uint4*)&hb[(n * 64 + d) * 512 + e0 + e8 * 8] =
        *(const uint4*)&eT[d * 40 + e8 * 8];
  }
}

// ---------------------------------------------------------------------------
// K3: per-row softmax denom + 2-bit adj pack (4096 blocks, wave-per-row).
// Reads raw adj (compulsory 33.5 MB stream) and overlaps it with the
// exp/score compute at full occupancy — measured best placement.
// ---------------------------------------------------------------------------
__global__ __launch_bounds__(256) void k3_rowstats(const int* __restrict__ adj,
                                                   float* __restrict__ ws) {
  const int n  = blockIdx.x >> 7;
  const int ib = blockIdx.x & 127;
  __shared__ float sd[3 * 512];
  const int t = threadIdx.x;
  ushort* adj2 = (ushort*)(ws + WS_ADJ2);

  #pragma unroll
  for (int k = 0; k < 6; k++) {
    int idx = t + 256 * k;
    sd[idx] = ws[WS_SDST + (idx >> 9) * 16384 + n * 512 + (idx & 511)];
  }
  __syncthreads();

  const int wave = t >> 6, lane = t & 63;
  const int i = ib * 4 + wave;
  const float s0 = ws[WS_SSRC + 0 * 16384 + n * 512 + i];
  const float s1 = ws[WS_SSRC + 1 * 16384 + n * 512 + i];
  const float s2 = ws[WS_SSRC + 2 * 16384 + n * 512 + i];
  const int* arow = &adj[(n * E_N + i) * E_N];

  float sum = 0.f;
  uint pack = 0;
  #pragma unroll
  for (int b = 0; b < 8; b++) {
    int j = b * 64 + lane;
    int a = arow[j];
    pack |= (uint)(a & 3) << (2 * b);
    if (a > 0) {
      float s = (a == 1) ? s0 : (a == 2 ? s1 : s2);
      float v = s + sd[(a - 1) * 512 + j];
      v = v > 0.f ? v : 0.2f * v;
      sum += __expf(v);
    }
  }
  #pragma unroll
  for (int off = 32; off >= 1; off >>= 1) sum += __shfl_xor(sum, off, 64);
  if (lane == 0) ws[WS_RINV + n * 512 + i] = 1.f / sum;
  adj2[(n * E_N + i) * 64 + lane] = (ushort)pack;   // 128 B/wave coalesced
}

// ---------------------------------------------------------------------------
// K4: out[n,j,d] = sum_i coef[n,i,j]*h[n,i,d] via MFMA, single pass over i.
// grid 32*16 (n = b>>4, j-tile 32 = b&15), block 256 = 4 waves. 4 i-chunks.
// hT staged via straight coalesced uint4 copies from transposed hTg;
// B-frags read b128 from LDS (stride 136 -> 2-way bank aliasing = free).
// ---------------------------------------------------------------------------
__global__ __launch_bounds__(256) void k4_out(float* __restrict__ ws,
                                              float* __restrict__ out) {
  const int n  = blockIdx.x >> 4;
  const int j0 = (blockIdx.x & 15) << 5;
  __shared__ ushort cT[32 * 136];
  __shared__ ushort hT[64 * 136];   // [d][i-local]
  __shared__ ushort aS[128 * 64];   // adj2 tile [i-local][u]
  __shared__ float sdT[3 * 32];
  __shared__ float ssT[3 * 128];
  __shared__ float riT[128];
  const int t = threadIdx.x;
  const ushort* hb = (const ushort*)(ws + WS_H);
  const ushort* adj2 = (const ushort*)(ws + WS_ADJ2);

  if (t < 96) sdT[t] = ws[WS_SDST + (t >> 5) * 16384 + n * 512 + j0 + (t & 31)];

  const int w = t >> 6, lane = t & 63;
  const int m15 = lane & 15, quad = lane >> 4;
  const int msub = w & 1, dhalf = w >> 1;
  const int c   = t & 31;            // j-local col (coef phase)
  const int rpb = t >> 5;            // 0..7 row-pair base
  const int u     = (j0 & 63) + c;   // ushort index within adj2 row
  const int shift = 2 * (j0 >> 6);   // bit position (block-uniform)

  float4x acc[2];
  acc[0] = (float4x)(0.f); acc[1] = (float4x)(0.f);

  for (int it = 0; it < 4; it++) {
    const int i0 = it << 7;

    // hT: 8192 ushorts = 1024 uint4, coalesced both sides
    #pragma unroll
    for (int k = 0; k < 4; k++) {
      int f = t + 256 * k;               // 0..1023
      int d = f >> 4, i16 = f & 15;
      *(uint4*)&hT[d * 136 + i16 * 8] =
          *(const uint4*)&hb[(n * 64 + d) * 512 + i0 + i16 * 8];
    }
    // adj2 tile: 8192 ushorts = 1024 uint4, coalesced
    #pragma unroll
    for (int k = 0; k < 4; k++) {
      int f = t + 256 * k;               // 0..1023
      int r = f >> 3, c8 = f & 7;
      *(uint4*)&aS[r * 64 + c8 * 8] =
          *(const uint4*)&adj2[(size_t)(n * E_N + i0 + r) * 64 + c8 * 8];
    }
    // riT/ssT: 512 floats
    #pragma unroll
    for (int k = 0; k < 2; k++) {
      int idx = t + 256 * k;
      if (idx < 128) riT[idx] = ws[WS_RINV + n * 512 + i0 + idx];
      else {
        int j2 = idx - 128;
        ssT[j2] = ws[WS_SSRC + (j2 >> 7) * 16384 + n * 512 + i0 + (j2 & 127)];
      }
    }
    __syncthreads();

    // coef -> bf16 pairs -> cT[j][i]; adj codes from LDS aS
    #pragma unroll
    for (int k = 0; k < 8; k++) {
      int r0 = 2 * (rpb + 8 * k);
      uint pack = 0;
      int a = (aS[r0 * 64 + u] >> shift) & 3;
      if (a > 0) {
        float v = ssT[(a - 1) * 128 + r0] + sdT[(a - 1) * 32 + c];
        v = v > 0.f ? v : 0.2f * v;
        pack = f2bf(__expf(v) * riT[r0]);
      }
      a = (aS[(r0 + 1) * 64 + u] >> shift) & 3;
      if (a > 0) {
        float v = ssT[(a - 1) * 128 + r0 + 1] + sdT[(a - 1) * 32 + c];
        v = v > 0.f ? v : 0.2f * v;
        pack |= (uint)f2bf(__expf(v) * riT[r0 + 1]) << 16;
      }
      *(uint*)&cT[c * 136 + r0] = pack;
    }
    __syncthreads();

    #pragma unroll
    for (int ks = 0; ks < 4; ks++) {
      short8x af = *(const short8x*)&cT[(msub * 16 + m15) * 136 + ks * 32 + quad * 8];
      #pragma unroll
      for (int dd = 0; dd < 2; dd++) {
        short8x bfv = *(const short8x*)&hT[((dhalf * 2 + dd) * 16 + m15) * 136 + ks * 32 + quad * 8];
        acc[dd] = __builtin_amdgcn_mfma_f32_16x16x32_bf16(af, bfv, acc[dd], 0, 0, 0);
      }
    }
    __syncthreads();
  }

  #pragma unroll
  for (int dd = 0; dd < 2; dd++)
    #pragma unroll
    for (int rg = 0; rg < 4; rg++) {
      int j = j0 + msub * 16 + quad * 4 + rg;
      out[(n * E_N + j) * 64 + (dhalf * 2 + dd) * 16 + m15] = acc[dd][rg];
    }
}

extern "C" void kernel_launch(void* const* d_in, const int* in_sizes, int n_in,
                              void* d_out, int out_size, void* d_ws, size_t ws_size,
                              hipStream_t stream) {
  fp input_state  = (fp)d_in[0];
  const int* adj  = (const int*)d_in[1];
  fp query_vec    = (fp)d_in[2];
  fp node_mask    = (fp)d_in[3];
  fp W_type       = (fp)d_in[4];
  fp a_type       = (fp)d_in[5];
  fp qattn_W1     = (fp)d_in[6];
  fp qattn_W2     = (fp)d_in[7];
  float* out = (float*)d_out;
  float* ws  = (float*)d_ws;

  k1_qgate<<<96, 512, 0, stream>>>(query_vec, W_type, a_type, qattn_W1, qattn_W2, ws);
  k2_h_s<<<512, 256, 0, stream>>>(input_state, node_mask, ws);
  k3_rowstats<<<32 * 128, 256, 0, stream>>>(adj, ws);
  k4_out<<<32 * 16, 256, 0, stream>>>(ws, out);
}